// Round 1
// baseline (427.355 us; speedup 1.0000x reference)
//
#include <hip/hip_runtime.h>

#define NFEAT 128

// ---------------- degree count ----------------
__global__ void count_deg_kernel(const int* __restrict__ dst, int* __restrict__ deg, int E) {
    int e = blockIdx.x * blockDim.x + threadIdx.x;
    if (e < E) atomicAdd(&deg[dst[e]], 1);
}

// ---------------- dinv + per-graph node counts ----------------
__global__ void node_init_kernel(const int* __restrict__ deg, const int* __restrict__ batch,
                                 float* __restrict__ dinv, float* __restrict__ gcnt, int N) {
    int v = blockIdx.x * blockDim.x + threadIdx.x;
    if (v < N) {
        dinv[v] = rsqrtf((float)(deg[v] + 1));   // +1 self-loop
        atomicAdd(&gcnt[batch[v]], 1.0f);
    }
}

// ---------------- single-block exclusive scan (8 elems/thread) ----------------
__global__ __launch_bounds__(1024) void scan_kernel(const int* __restrict__ deg,
                                                    int* __restrict__ row_start,
                                                    int* __restrict__ cursor, int n) {
    __shared__ int sm[1024];
    const int tid = threadIdx.x;
    int carry = 0;
    for (int base = 0; base < n; base += 1024 * 8) {
        int i0 = base + tid * 8;
        int v[8];
        int s = 0;
#pragma unroll
        for (int j = 0; j < 8; ++j) {
            v[j] = (i0 + j < n) ? deg[i0 + j] : 0;
            s += v[j];
        }
        sm[tid] = s;
        __syncthreads();
        for (int off = 1; off < 1024; off <<= 1) {
            int t = (tid >= off) ? sm[tid - off] : 0;
            __syncthreads();
            sm[tid] += t;
            __syncthreads();
        }
        int run = carry + sm[tid] - s;   // exclusive start for this thread's 8 elems
        int total = sm[1023];
#pragma unroll
        for (int j = 0; j < 8; ++j) {
            if (i0 + j < n) { row_start[i0 + j] = run; cursor[i0 + j] = run; }
            run += v[j];
        }
        carry += total;
        __syncthreads();
    }
}

// ---------------- CSR fill ----------------
__global__ void csr_fill_kernel(const int* __restrict__ src, const int* __restrict__ dst,
                                int* __restrict__ cursor, int* __restrict__ csr_src, int E) {
    int e = blockIdx.x * blockDim.x + threadIdx.x;
    if (e < E) {
        int pos = atomicAdd(&cursor[dst[e]], 1);
        csr_src[pos] = src[e];
    }
}

// ---------------- GEMM: out[r][c] = (sum_k X[r][k]*W[k][c]) * dinv[r] ----------------
// block 256 threads: 32 rows x 128 cols. thread: 2 rows x 8 cols (cols t16+16j).
__global__ __launch_bounds__(256) void gemm_scale_kernel(const float* __restrict__ X,
                                                         const float* __restrict__ W,
                                                         const float* __restrict__ dinv,
                                                         float* __restrict__ out, int nrows) {
    __shared__ float xs[32][132];   // pad 132: bank (4r+k)%32, conflict-free
    __shared__ float ws[64][128];   // K-phase slice
    const int tid = threadIdx.x;
    const int row0 = blockIdx.x * 32;

    // stage 32 rows of X (full K=128), float4-coalesced
    for (int idx = tid; idx < 32 * 32; idx += 256) {
        int r = idx >> 5, q = idx & 31;
        float4 val;
        if (row0 + r < nrows)
            val = ((const float4*)(X + (size_t)(row0 + r) * NFEAT))[q];
        else
            val = make_float4(0.f, 0.f, 0.f, 0.f);
        *(float4*)&xs[r][q * 4] = val;
    }

    const int t16 = tid & 15;
    const int rg = tid >> 4;          // 0..15
    const int r0 = rg * 2, r1 = rg * 2 + 1;
    float acc0[8] = {0, 0, 0, 0, 0, 0, 0, 0};
    float acc1[8] = {0, 0, 0, 0, 0, 0, 0, 0};

    for (int p = 0; p < 2; ++p) {
        __syncthreads();   // xs staged (p=0) / previous ws consumed (p=1)
        for (int idx = tid; idx < 64 * 32; idx += 256) {
            int kk = idx >> 5, q = idx & 31;
            *(float4*)&ws[kk][q * 4] = ((const float4*)(W + (size_t)(p * 64 + kk) * NFEAT))[q];
        }
        __syncthreads();
#pragma unroll 4
        for (int k = 0; k < 64; ++k) {
            float x0 = xs[r0][p * 64 + k];
            float x1 = xs[r1][p * 64 + k];
#pragma unroll
            for (int j = 0; j < 8; ++j) {
                float w = ws[k][t16 + 16 * j];   // 16 addrs, 4-lane broadcast: conflict-free
                acc0[j] = fmaf(x0, w, acc0[j]);
                acc1[j] = fmaf(x1, w, acc1[j]);
            }
        }
    }

    int orow = row0 + r0;
    if (orow < nrows) {
        float d = dinv[orow];
        float* o = out + (size_t)orow * NFEAT;
#pragma unroll
        for (int j = 0; j < 8; ++j) o[t16 + 16 * j] = acc0[j] * d;
    }
    orow = row0 + r1;
    if (orow < nrows) {
        float d = dinv[orow];
        float* o = out + (size_t)orow * NFEAT;
#pragma unroll
        for (int j = 0; j < 8; ++j) o[t16 + 16 * j] = acc1[j] * d;
    }
}

// ---------------- aggregation + relu (layer 1): out[v] = relu(dinv[v]*(hp[v]+sum hp[src]) + b) ----------------
__global__ __launch_bounds__(128) void agg_relu_kernel(const float* __restrict__ hp,
                                                       const int* __restrict__ row_start,
                                                       const int* __restrict__ deg,
                                                       const int* __restrict__ csr_src,
                                                       const float* __restrict__ dinv,
                                                       const float* __restrict__ bias,
                                                       float* __restrict__ out, int N) {
    const int v = blockIdx.x;
    const int t = threadIdx.x;
    float acc = hp[(size_t)v * NFEAT + t];    // self-loop term
    const int s = row_start[v];
    const int e = s + deg[v];
    int i = s;
    for (; i + 4 <= e; i += 4) {
        int u0 = csr_src[i], u1 = csr_src[i + 1], u2 = csr_src[i + 2], u3 = csr_src[i + 3];
        float a0 = hp[(size_t)u0 * NFEAT + t];
        float a1 = hp[(size_t)u1 * NFEAT + t];
        float a2 = hp[(size_t)u2 * NFEAT + t];
        float a3 = hp[(size_t)u3 * NFEAT + t];
        acc += a0 + a1 + a2 + a3;
    }
    for (; i < e; ++i) acc += hp[(size_t)csr_src[i] * NFEAT + t];
    out[(size_t)v * NFEAT + t] = fmaxf(fmaf(acc, dinv[v], bias[t]), 0.0f);
}

// ---------------- aggregation + relu + dot(lin_W) + pool-sum (layer 2 fused) ----------------
__global__ __launch_bounds__(128) void agg_pool_kernel(const float* __restrict__ hp,
                                                       const int* __restrict__ row_start,
                                                       const int* __restrict__ deg,
                                                       const int* __restrict__ csr_src,
                                                       const float* __restrict__ dinv,
                                                       const float* __restrict__ bias,
                                                       const float* __restrict__ linW,
                                                       const int* __restrict__ batch,
                                                       float* __restrict__ gsum, int N) {
    const int v = blockIdx.x;
    const int t = threadIdx.x;
    float acc = hp[(size_t)v * NFEAT + t];
    const int s = row_start[v];
    const int e = s + deg[v];
    int i = s;
    for (; i + 4 <= e; i += 4) {
        int u0 = csr_src[i], u1 = csr_src[i + 1], u2 = csr_src[i + 2], u3 = csr_src[i + 3];
        float a0 = hp[(size_t)u0 * NFEAT + t];
        float a1 = hp[(size_t)u1 * NFEAT + t];
        float a2 = hp[(size_t)u2 * NFEAT + t];
        float a3 = hp[(size_t)u3 * NFEAT + t];
        acc += a0 + a1 + a2 + a3;
    }
    for (; i < e; ++i) acc += hp[(size_t)csr_src[i] * NFEAT + t];
    float val = fmaxf(fmaf(acc, dinv[v], bias[t]), 0.0f);
    float sc = val * linW[t];
#pragma unroll
    for (int off = 32; off > 0; off >>= 1) sc += __shfl_down(sc, off, 64);
    __shared__ float red;
    if (t == 64) red = sc;
    __syncthreads();
    if (t == 0) atomicAdd(&gsum[batch[v]], sc + red);
}

// ---------------- finalize: out[g] = gsum[g]/max(cnt,1) + lin_b ----------------
__global__ void finalize_kernel(const float* __restrict__ gsum, const float* __restrict__ gcnt,
                                const float* __restrict__ linb, float* __restrict__ out, int G) {
    int g = blockIdx.x * blockDim.x + threadIdx.x;
    if (g < G) out[g] = gsum[g] / fmaxf(gcnt[g], 1.0f) + linb[0];
}

extern "C" void kernel_launch(void* const* d_in, const int* in_sizes, int n_in,
                              void* d_out, int out_size, void* d_ws, size_t ws_size,
                              hipStream_t stream) {
    const float* x    = (const float*)d_in[0];
    const int*   eidx = (const int*)d_in[1];
    const int*   batch= (const int*)d_in[2];
    const float* W1   = (const float*)d_in[3];
    const float* b1   = (const float*)d_in[4];
    const float* W2   = (const float*)d_in[5];
    const float* b2   = (const float*)d_in[6];
    const float* linW = (const float*)d_in[7];
    const float* linb = (const float*)d_in[8];
    float* out = (float*)d_out;

    const int N = in_sizes[0] / NFEAT;   // 50000
    const int E = in_sizes[1] / 2;       // 800000
    const int G = out_size;              // 256
    const int* src = eidx;
    const int* dst = eidx + E;

    // workspace layout
    char* p = (char*)d_ws;
    float* hpA      = (float*)p; p += (size_t)N * NFEAT * sizeof(float);
    float* hpB      = (float*)p; p += (size_t)N * NFEAT * sizeof(float);
    int*   csr_src  = (int*)p;   p += (size_t)E * sizeof(int);
    int*   row_start= (int*)p;   p += (size_t)(N + 4) * sizeof(int);
    int*   cursor   = (int*)p;   p += (size_t)N * sizeof(int);
    float* dinv     = (float*)p; p += (size_t)N * sizeof(float);
    int*   deg      = (int*)p;   p += (size_t)N * sizeof(int);
    float* gsum     = (float*)p; p += (size_t)G * sizeof(float);
    float* gcnt     = (float*)p; p += (size_t)G * sizeof(float);
    (void)ws_size; (void)n_in;

    // zero deg + gsum + gcnt (contiguous)
    hipMemsetAsync(deg, 0, (size_t)(N + 2 * G) * sizeof(float), stream);

    count_deg_kernel<<<(E + 255) / 256, 256, 0, stream>>>(dst, deg, E);
    node_init_kernel<<<(N + 255) / 256, 256, 0, stream>>>(deg, batch, dinv, gcnt, N);
    scan_kernel<<<1, 1024, 0, stream>>>(deg, row_start, cursor, N);
    csr_fill_kernel<<<(E + 255) / 256, 256, 0, stream>>>(src, dst, cursor, csr_src, E);

    gemm_scale_kernel<<<(N + 31) / 32, 256, 0, stream>>>(x, W1, dinv, hpA, N);
    agg_relu_kernel<<<N, 128, 0, stream>>>(hpA, row_start, deg, csr_src, dinv, b1, hpB, N);
    gemm_scale_kernel<<<(N + 31) / 32, 256, 0, stream>>>(hpB, W2, dinv, hpA, N);
    agg_pool_kernel<<<N, 128, 0, stream>>>(hpA, row_start, deg, csr_src, dinv, b2, linW, batch, gsum, N);
    finalize_kernel<<<(G + 63) / 64, 64, 0, stream>>>(gsum, gcnt, linb, out, G);
}

// Round 2
// 349.371 us; speedup vs baseline: 1.2232x; 1.2232x over previous
//
#include <hip/hip_runtime.h>

#define NFEAT 128

__device__ inline float4 f4add(float4 a, float4 b) {
    return make_float4(a.x + b.x, a.y + b.y, a.z + b.z, a.w + b.w);
}

// ---------------- degree count ----------------
__global__ void count_deg_kernel(const int* __restrict__ dst, int* __restrict__ deg, int E) {
    int e = blockIdx.x * blockDim.x + threadIdx.x;
    if (e < E) atomicAdd(&deg[dst[e]], 1);
}

// ---------------- dinv + per-graph node counts ----------------
__global__ void node_init_kernel(const int* __restrict__ deg, const int* __restrict__ batch,
                                 float* __restrict__ dinv, float* __restrict__ gcnt, int N) {
    int v = blockIdx.x * blockDim.x + threadIdx.x;
    if (v < N) {
        dinv[v] = rsqrtf((float)(deg[v] + 1));   // +1 self-loop
        atomicAdd(&gcnt[batch[v]], 1.0f);
    }
}

// ---------------- multi-block scan, stage 1: per-block (1024 elems) sums ----------------
__global__ __launch_bounds__(256) void scan_partial_kernel(const int* __restrict__ deg,
                                                           int* __restrict__ bsum, int n) {
    __shared__ int sm[4];
    const int tid = threadIdx.x;
    const int base = blockIdx.x * 1024 + tid * 4;
    int s = 0;
#pragma unroll
    for (int j = 0; j < 4; ++j) s += (base + j < n) ? deg[base + j] : 0;
#pragma unroll
    for (int off = 32; off; off >>= 1) s += __shfl_down(s, off);
    if ((tid & 63) == 0) sm[tid >> 6] = s;
    __syncthreads();
    if (tid == 0) bsum[blockIdx.x] = sm[0] + sm[1] + sm[2] + sm[3];
}

// ---------------- stage 2: exclusive scan of block sums (single wave, nb<=64) ----------------
__global__ __launch_bounds__(64) void scan_offsets_kernel(const int* __restrict__ bsum,
                                                          int* __restrict__ boff, int nb) {
    const int l = threadIdx.x;
    int orig = (l < nb) ? bsum[l] : 0;
    int v = orig;
#pragma unroll
    for (int off = 1; off < 64; off <<= 1) {
        int t = __shfl_up(v, off);
        if (l >= off) v += t;
    }
    if (l < nb) boff[l] = v - orig;   // exclusive
}

// ---------------- stage 3: per-block scan + global offset, write row_start & cursor ----------------
__global__ __launch_bounds__(256) void scan_final_kernel(const int* __restrict__ deg,
                                                         const int* __restrict__ boff,
                                                         int* __restrict__ row_start,
                                                         int* __restrict__ cursor, int n) {
    __shared__ int wsum[4];
    const int tid = threadIdx.x;
    const int lane = tid & 63;
    const int w = tid >> 6;
    const int base = blockIdx.x * 1024 + tid * 4;
    int v[4];
    int s = 0;
#pragma unroll
    for (int j = 0; j < 4; ++j) {
        v[j] = (base + j < n) ? deg[base + j] : 0;
        s += v[j];
    }
    int incl = s;
#pragma unroll
    for (int off = 1; off < 64; off <<= 1) {
        int t = __shfl_up(incl, off);
        if (lane >= off) incl += t;
    }
    if (lane == 63) wsum[w] = incl;
    __syncthreads();
    int woff = 0;
    for (int i = 0; i < w; ++i) woff += wsum[i];
    int run = boff[blockIdx.x] + woff + (incl - s);   // exclusive start for this thread
#pragma unroll
    for (int j = 0; j < 4; ++j) {
        if (base + j < n) { row_start[base + j] = run; cursor[base + j] = run; }
        run += v[j];
    }
}

// ---------------- CSR fill ----------------
__global__ void csr_fill_kernel(const int* __restrict__ src, const int* __restrict__ dst,
                                int* __restrict__ cursor, int* __restrict__ csr_src, int E) {
    int e = blockIdx.x * blockDim.x + threadIdx.x;
    if (e < E) {
        int pos = atomicAdd(&cursor[dst[e]], 1);
        csr_src[pos] = src[e];
    }
}

// ---------------- GEMM: out[r][c] = (sum_k X[r][k]*W[k][c]) * dinv[r] ----------------
// block 256 threads, tile 64 rows x 128 cols, thread = 4 rows x 8 cols.
__global__ __launch_bounds__(256) void gemm_scale_kernel(const float* __restrict__ X,
                                                         const float* __restrict__ W,
                                                         const float* __restrict__ dinv,
                                                         float* __restrict__ out, int nrows) {
    __shared__ float xs[64][132];   // full K=128 (+4 pad)
    __shared__ float ws[64][128];   // K-phase slice of W
    const int tid = threadIdx.x;
    const int row0 = blockIdx.x * 64;
    const int rt = tid >> 4;        // 0..15 -> rows 4rt..4rt+3
    const int ct = tid & 15;        // cols 8ct..8ct+7

    // stage X tile (64 rows, full K), float4-coalesced
    for (int idx = tid; idx < 64 * 32; idx += 256) {
        int r = idx >> 5, q = idx & 31;
        float4 val = make_float4(0.f, 0.f, 0.f, 0.f);
        if (row0 + r < nrows) val = ((const float4*)(X + (size_t)(row0 + r) * NFEAT))[q];
        *(float4*)&xs[r][q * 4] = val;
    }

    float acc[4][8];
#pragma unroll
    for (int j = 0; j < 4; ++j)
#pragma unroll
        for (int i = 0; i < 8; ++i) acc[j][i] = 0.f;

    for (int p = 0; p < 2; ++p) {
        __syncthreads();   // xs staged (p=0) / prev ws consumed (p=1)
        for (int idx = tid; idx < 64 * 32; idx += 256) {
            int kk = idx >> 5, q = idx & 31;
            *(float4*)&ws[kk][q * 4] = ((const float4*)(W + (size_t)(p * 64 + kk) * NFEAT))[q];
        }
        __syncthreads();
#pragma unroll 4
        for (int k = 0; k < 64; ++k) {
            const int ka = p * 64 + k;
            float x0 = xs[4 * rt + 0][ka];
            float x1 = xs[4 * rt + 1][ka];
            float x2 = xs[4 * rt + 2][ka];
            float x3 = xs[4 * rt + 3][ka];
            float4 w0 = *(const float4*)&ws[k][8 * ct];
            float4 w1 = *(const float4*)&ws[k][8 * ct + 4];
            acc[0][0] = fmaf(x0, w0.x, acc[0][0]); acc[0][1] = fmaf(x0, w0.y, acc[0][1]);
            acc[0][2] = fmaf(x0, w0.z, acc[0][2]); acc[0][3] = fmaf(x0, w0.w, acc[0][3]);
            acc[0][4] = fmaf(x0, w1.x, acc[0][4]); acc[0][5] = fmaf(x0, w1.y, acc[0][5]);
            acc[0][6] = fmaf(x0, w1.z, acc[0][6]); acc[0][7] = fmaf(x0, w1.w, acc[0][7]);
            acc[1][0] = fmaf(x1, w0.x, acc[1][0]); acc[1][1] = fmaf(x1, w0.y, acc[1][1]);
            acc[1][2] = fmaf(x1, w0.z, acc[1][2]); acc[1][3] = fmaf(x1, w0.w, acc[1][3]);
            acc[1][4] = fmaf(x1, w1.x, acc[1][4]); acc[1][5] = fmaf(x1, w1.y, acc[1][5]);
            acc[1][6] = fmaf(x1, w1.z, acc[1][6]); acc[1][7] = fmaf(x1, w1.w, acc[1][7]);
            acc[2][0] = fmaf(x2, w0.x, acc[2][0]); acc[2][1] = fmaf(x2, w0.y, acc[2][1]);
            acc[2][2] = fmaf(x2, w0.z, acc[2][2]); acc[2][3] = fmaf(x2, w0.w, acc[2][3]);
            acc[2][4] = fmaf(x2, w1.x, acc[2][4]); acc[2][5] = fmaf(x2, w1.y, acc[2][5]);
            acc[2][6] = fmaf(x2, w1.z, acc[2][6]); acc[2][7] = fmaf(x2, w1.w, acc[2][7]);
            acc[3][0] = fmaf(x3, w0.x, acc[3][0]); acc[3][1] = fmaf(x3, w0.y, acc[3][1]);
            acc[3][2] = fmaf(x3, w0.z, acc[3][2]); acc[3][3] = fmaf(x3, w0.w, acc[3][3]);
            acc[3][4] = fmaf(x3, w1.x, acc[3][4]); acc[3][5] = fmaf(x3, w1.y, acc[3][5]);
            acc[3][6] = fmaf(x3, w1.z, acc[3][6]); acc[3][7] = fmaf(x3, w1.w, acc[3][7]);
        }
    }

#pragma unroll
    for (int j = 0; j < 4; ++j) {
        int row = row0 + 4 * rt + j;
        if (row < nrows) {
            float dv = dinv[row];
            float4 o0 = make_float4(acc[j][0] * dv, acc[j][1] * dv, acc[j][2] * dv, acc[j][3] * dv);
            float4 o1 = make_float4(acc[j][4] * dv, acc[j][5] * dv, acc[j][6] * dv, acc[j][7] * dv);
            *(float4*)(out + (size_t)row * NFEAT + 8 * ct) = o0;
            *(float4*)(out + (size_t)row * NFEAT + 8 * ct + 4) = o1;
        }
    }
}

// ---------------- aggregation + relu (layer 1), wave-per-node float4 ----------------
// lane half (0/1) = edge parity, lane&31 = float4 chunk of the 128-feat row.
__global__ __launch_bounds__(256) void agg_relu_kernel(const float4* __restrict__ hp,
                                                       const int* __restrict__ row_start,
                                                       const int* __restrict__ deg,
                                                       const int* __restrict__ csr_src,
                                                       const float* __restrict__ dinv,
                                                       const float4* __restrict__ bias,
                                                       float4* __restrict__ out, int N) {
    const int wid = (blockIdx.x * 256 + threadIdx.x) >> 6;
    if (wid >= N) return;
    const int lane = threadIdx.x & 63;
    const int half = lane >> 5;
    const int c = lane & 31;
    const size_t vb = (size_t)wid * 32;
    float4 acc = make_float4(0.f, 0.f, 0.f, 0.f);
    if (!half) acc = hp[vb + c];          // self-loop term (counted once)
    const int s = row_start[wid];
    const int d = deg[wid];
    int i = 0;
    for (; i + 8 <= d; i += 8) {
        int u0 = csr_src[s + i + 0 + half];
        int u1 = csr_src[s + i + 2 + half];
        int u2 = csr_src[s + i + 4 + half];
        int u3 = csr_src[s + i + 6 + half];
        float4 a0 = hp[(size_t)u0 * 32 + c];
        float4 a1 = hp[(size_t)u1 * 32 + c];
        float4 a2 = hp[(size_t)u2 * 32 + c];
        float4 a3 = hp[(size_t)u3 * 32 + c];
        acc = f4add(acc, f4add(f4add(a0, a1), f4add(a2, a3)));
    }
    for (; i + 2 <= d; i += 2) {
        int u = csr_src[s + i + half];
        acc = f4add(acc, hp[(size_t)u * 32 + c]);
    }
    if (i + half < d) {                   // odd leftover -> half 0 only
        int u = csr_src[s + i + half];
        acc = f4add(acc, hp[(size_t)u * 32 + c]);
    }
    // merge halves
    acc.x += __shfl_xor(acc.x, 32);
    acc.y += __shfl_xor(acc.y, 32);
    acc.z += __shfl_xor(acc.z, 32);
    acc.w += __shfl_xor(acc.w, 32);
    const float dv = dinv[wid];
    const float4 bb = bias[c];
    float4 val;
    val.x = fmaxf(fmaf(acc.x, dv, bb.x), 0.f);
    val.y = fmaxf(fmaf(acc.y, dv, bb.y), 0.f);
    val.z = fmaxf(fmaf(acc.z, dv, bb.z), 0.f);
    val.w = fmaxf(fmaf(acc.w, dv, bb.w), 0.f);
    if (!half) out[vb + c] = val;
}

// ---------------- aggregation + relu + dot(lin_W) + pool-sum (layer 2 fused) ----------------
__global__ __launch_bounds__(256) void agg_pool_kernel(const float4* __restrict__ hp,
                                                       const int* __restrict__ row_start,
                                                       const int* __restrict__ deg,
                                                       const int* __restrict__ csr_src,
                                                       const float* __restrict__ dinv,
                                                       const float4* __restrict__ bias,
                                                       const float4* __restrict__ linW,
                                                       const int* __restrict__ batch,
                                                       float* __restrict__ gsum, int N) {
    const int wid = (blockIdx.x * 256 + threadIdx.x) >> 6;
    if (wid >= N) return;
    const int lane = threadIdx.x & 63;
    const int half = lane >> 5;
    const int c = lane & 31;
    const size_t vb = (size_t)wid * 32;
    float4 acc = make_float4(0.f, 0.f, 0.f, 0.f);
    if (!half) acc = hp[vb + c];
    const int s = row_start[wid];
    const int d = deg[wid];
    int i = 0;
    for (; i + 8 <= d; i += 8) {
        int u0 = csr_src[s + i + 0 + half];
        int u1 = csr_src[s + i + 2 + half];
        int u2 = csr_src[s + i + 4 + half];
        int u3 = csr_src[s + i + 6 + half];
        float4 a0 = hp[(size_t)u0 * 32 + c];
        float4 a1 = hp[(size_t)u1 * 32 + c];
        float4 a2 = hp[(size_t)u2 * 32 + c];
        float4 a3 = hp[(size_t)u3 * 32 + c];
        acc = f4add(acc, f4add(f4add(a0, a1), f4add(a2, a3)));
    }
    for (; i + 2 <= d; i += 2) {
        int u = csr_src[s + i + half];
        acc = f4add(acc, hp[(size_t)u * 32 + c]);
    }
    if (i + half < d) {
        int u = csr_src[s + i + half];
        acc = f4add(acc, hp[(size_t)u * 32 + c]);
    }
    acc.x += __shfl_xor(acc.x, 32);
    acc.y += __shfl_xor(acc.y, 32);
    acc.z += __shfl_xor(acc.z, 32);
    acc.w += __shfl_xor(acc.w, 32);
    const float dv = dinv[wid];
    const float4 bb = bias[c];
    const float4 lw = linW[c];
    float sc = fmaxf(fmaf(acc.x, dv, bb.x), 0.f) * lw.x
             + fmaxf(fmaf(acc.y, dv, bb.y), 0.f) * lw.y
             + fmaxf(fmaf(acc.z, dv, bb.z), 0.f) * lw.z
             + fmaxf(fmaf(acc.w, dv, bb.w), 0.f) * lw.w;
#pragma unroll
    for (int off = 16; off; off >>= 1) sc += __shfl_xor(sc, off);
    if (lane == 0) atomicAdd(&gsum[batch[wid]], sc);
}

// ---------------- finalize: out[g] = gsum[g]/max(cnt,1) + lin_b ----------------
__global__ void finalize_kernel(const float* __restrict__ gsum, const float* __restrict__ gcnt,
                                const float* __restrict__ linb, float* __restrict__ out, int G) {
    int g = blockIdx.x * blockDim.x + threadIdx.x;
    if (g < G) out[g] = gsum[g] / fmaxf(gcnt[g], 1.0f) + linb[0];
}

extern "C" void kernel_launch(void* const* d_in, const int* in_sizes, int n_in,
                              void* d_out, int out_size, void* d_ws, size_t ws_size,
                              hipStream_t stream) {
    const float* x    = (const float*)d_in[0];
    const int*   eidx = (const int*)d_in[1];
    const int*   batch= (const int*)d_in[2];
    const float* W1   = (const float*)d_in[3];
    const float* b1   = (const float*)d_in[4];
    const float* W2   = (const float*)d_in[5];
    const float* b2   = (const float*)d_in[6];
    const float* linW = (const float*)d_in[7];
    const float* linb = (const float*)d_in[8];
    float* out = (float*)d_out;

    const int N = in_sizes[0] / NFEAT;   // 50000
    const int E = in_sizes[1] / 2;       // 800000
    const int G = out_size;              // 256
    const int* src = eidx;
    const int* dst = eidx + E;
    const int NB = (N + 1023) / 1024;    // scan blocks (49 <= 64)

    // workspace layout
    char* p = (char*)d_ws;
    float* hpA      = (float*)p; p += (size_t)N * NFEAT * sizeof(float);
    float* hpB      = (float*)p; p += (size_t)N * NFEAT * sizeof(float);
    int*   csr_src  = (int*)p;   p += (size_t)E * sizeof(int);
    int*   row_start= (int*)p;   p += (size_t)(N + 4) * sizeof(int);
    int*   cursor   = (int*)p;   p += (size_t)N * sizeof(int);
    float* dinv     = (float*)p; p += (size_t)N * sizeof(float);
    int*   deg      = (int*)p;   p += (size_t)N * sizeof(int);
    float* gsum     = (float*)p; p += (size_t)G * sizeof(float);
    float* gcnt     = (float*)p; p += (size_t)G * sizeof(float);
    int*   bsum     = (int*)p;   p += 64 * sizeof(int);
    int*   boff     = (int*)p;   p += 64 * sizeof(int);
    (void)ws_size; (void)n_in;

    // zero deg + gsum + gcnt (contiguous)
    hipMemsetAsync(deg, 0, (size_t)(N + 2 * G) * sizeof(float), stream);

    count_deg_kernel<<<(E + 255) / 256, 256, 0, stream>>>(dst, deg, E);
    node_init_kernel<<<(N + 255) / 256, 256, 0, stream>>>(deg, batch, dinv, gcnt, N);
    scan_partial_kernel<<<NB, 256, 0, stream>>>(deg, bsum, N);
    scan_offsets_kernel<<<1, 64, 0, stream>>>(bsum, boff, NB);
    scan_final_kernel<<<NB, 256, 0, stream>>>(deg, boff, row_start, cursor, N);
    csr_fill_kernel<<<(E + 255) / 256, 256, 0, stream>>>(src, dst, cursor, csr_src, E);

    gemm_scale_kernel<<<(N + 63) / 64, 256, 0, stream>>>(x, W1, dinv, hpA, N);
    agg_relu_kernel<<<(N * 64 + 255) / 256, 256, 0, stream>>>((const float4*)hpA, row_start, deg,
                                                              csr_src, dinv, (const float4*)b1,
                                                              (float4*)hpB, N);
    gemm_scale_kernel<<<(N + 63) / 64, 256, 0, stream>>>(hpB, W2, dinv, hpA, N);
    agg_pool_kernel<<<(N * 64 + 255) / 256, 256, 0, stream>>>((const float4*)hpA, row_start, deg,
                                                              csr_src, dinv, (const float4*)b2,
                                                              (const float4*)linW, batch, gsum, N);
    finalize_kernel<<<(G + 63) / 64, 64, 0, stream>>>(gsum, gcnt, linb, out, G);
}

// Round 3
// 336.406 us; speedup vs baseline: 1.2704x; 1.0385x over previous
//
#include <hip/hip_runtime.h>

#define NFEAT 128

typedef unsigned int uint;

__device__ inline float bf2f(unsigned short u) {
    return __uint_as_float(((uint)u) << 16);
}
__device__ inline unsigned short f2bf(float f) {   // round-nearest-even
    uint u = __float_as_uint(f);
    return (unsigned short)((u + 0x7fffu + ((u >> 16) & 1u)) >> 16);
}
__device__ inline uint pack2(float lo, float hi) {
    return (uint)f2bf(lo) | ((uint)f2bf(hi) << 16);
}
__device__ inline void acc_bf4(float4& acc, ushort4 a) {
    acc.x += bf2f(a.x); acc.y += bf2f(a.y); acc.z += bf2f(a.z); acc.w += bf2f(a.w);
}

// ---------------- degree count ----------------
__global__ void count_deg_kernel(const int* __restrict__ dst, int* __restrict__ deg, int E) {
    int e = blockIdx.x * blockDim.x + threadIdx.x;
    if (e < E) atomicAdd(&deg[dst[e]], 1);
}

// ---------------- dinv + per-graph node counts ----------------
__global__ void node_init_kernel(const int* __restrict__ deg, const int* __restrict__ batch,
                                 float* __restrict__ dinv, float* __restrict__ gcnt, int N) {
    int v = blockIdx.x * blockDim.x + threadIdx.x;
    if (v < N) {
        dinv[v] = rsqrtf((float)(deg[v] + 1));   // +1 self-loop
        atomicAdd(&gcnt[batch[v]], 1.0f);
    }
}

// ---------------- multi-block scan, stage 1 ----------------
__global__ __launch_bounds__(256) void scan_partial_kernel(const int* __restrict__ deg,
                                                           int* __restrict__ bsum, int n) {
    __shared__ int sm[4];
    const int tid = threadIdx.x;
    const int base = blockIdx.x * 1024 + tid * 4;
    int s = 0;
#pragma unroll
    for (int j = 0; j < 4; ++j) s += (base + j < n) ? deg[base + j] : 0;
#pragma unroll
    for (int off = 32; off; off >>= 1) s += __shfl_down(s, off);
    if ((tid & 63) == 0) sm[tid >> 6] = s;
    __syncthreads();
    if (tid == 0) bsum[blockIdx.x] = sm[0] + sm[1] + sm[2] + sm[3];
}

// ---------------- stage 2: exclusive scan of block sums ----------------
__global__ __launch_bounds__(64) void scan_offsets_kernel(const int* __restrict__ bsum,
                                                          int* __restrict__ boff, int nb) {
    const int l = threadIdx.x;
    int orig = (l < nb) ? bsum[l] : 0;
    int v = orig;
#pragma unroll
    for (int off = 1; off < 64; off <<= 1) {
        int t = __shfl_up(v, off);
        if (l >= off) v += t;
    }
    if (l < nb) boff[l] = v - orig;
}

// ---------------- stage 3: final scan ----------------
__global__ __launch_bounds__(256) void scan_final_kernel(const int* __restrict__ deg,
                                                         const int* __restrict__ boff,
                                                         int* __restrict__ row_start,
                                                         int* __restrict__ cursor, int n) {
    __shared__ int wsum[4];
    const int tid = threadIdx.x;
    const int lane = tid & 63;
    const int w = tid >> 6;
    const int base = blockIdx.x * 1024 + tid * 4;
    int v[4];
    int s = 0;
#pragma unroll
    for (int j = 0; j < 4; ++j) {
        v[j] = (base + j < n) ? deg[base + j] : 0;
        s += v[j];
    }
    int incl = s;
#pragma unroll
    for (int off = 1; off < 64; off <<= 1) {
        int t = __shfl_up(incl, off);
        if (lane >= off) incl += t;
    }
    if (lane == 63) wsum[w] = incl;
    __syncthreads();
    int woff = 0;
    for (int i = 0; i < w; ++i) woff += wsum[i];
    int run = boff[blockIdx.x] + woff + (incl - s);
#pragma unroll
    for (int j = 0; j < 4; ++j) {
        if (base + j < n) { row_start[base + j] = run; cursor[base + j] = run; }
        run += v[j];
    }
}

// ---------------- CSR fill ----------------
__global__ void csr_fill_kernel(const int* __restrict__ src, const int* __restrict__ dst,
                                int* __restrict__ cursor, int* __restrict__ csr_src, int E) {
    int e = blockIdx.x * blockDim.x + threadIdx.x;
    if (e < E) {
        int pos = atomicAdd(&cursor[dst[e]], 1);
        csr_src[pos] = src[e];
    }
}

// ---------------- GEMM: out_bf16[r][c] = (sum_k X[r][k]*W[k][c]) * dinv[r] ----------------
// block 256 threads, tile 64 rows x 128 cols, thread = 4 rows x 8 cols. f32 math, bf16 store.
__global__ __launch_bounds__(256) void gemm_scale_kernel(const float* __restrict__ X,
                                                         const float* __restrict__ W,
                                                         const float* __restrict__ dinv,
                                                         unsigned short* __restrict__ out,
                                                         int nrows) {
    __shared__ float xs[64][132];
    __shared__ float ws[64][128];
    const int tid = threadIdx.x;
    const int row0 = blockIdx.x * 64;
    const int rt = tid >> 4;
    const int ct = tid & 15;

    for (int idx = tid; idx < 64 * 32; idx += 256) {
        int r = idx >> 5, q = idx & 31;
        float4 val = make_float4(0.f, 0.f, 0.f, 0.f);
        if (row0 + r < nrows) val = ((const float4*)(X + (size_t)(row0 + r) * NFEAT))[q];
        *(float4*)&xs[r][q * 4] = val;
    }

    float acc[4][8];
#pragma unroll
    for (int j = 0; j < 4; ++j)
#pragma unroll
        for (int i = 0; i < 8; ++i) acc[j][i] = 0.f;

    for (int p = 0; p < 2; ++p) {
        __syncthreads();
        for (int idx = tid; idx < 64 * 32; idx += 256) {
            int kk = idx >> 5, q = idx & 31;
            *(float4*)&ws[kk][q * 4] = ((const float4*)(W + (size_t)(p * 64 + kk) * NFEAT))[q];
        }
        __syncthreads();
#pragma unroll 4
        for (int k = 0; k < 64; ++k) {
            const int ka = p * 64 + k;
            float x0 = xs[4 * rt + 0][ka];
            float x1 = xs[4 * rt + 1][ka];
            float x2 = xs[4 * rt + 2][ka];
            float x3 = xs[4 * rt + 3][ka];
            float4 w0 = *(const float4*)&ws[k][8 * ct];
            float4 w1 = *(const float4*)&ws[k][8 * ct + 4];
            acc[0][0] = fmaf(x0, w0.x, acc[0][0]); acc[0][1] = fmaf(x0, w0.y, acc[0][1]);
            acc[0][2] = fmaf(x0, w0.z, acc[0][2]); acc[0][3] = fmaf(x0, w0.w, acc[0][3]);
            acc[0][4] = fmaf(x0, w1.x, acc[0][4]); acc[0][5] = fmaf(x0, w1.y, acc[0][5]);
            acc[0][6] = fmaf(x0, w1.z, acc[0][6]); acc[0][7] = fmaf(x0, w1.w, acc[0][7]);
            acc[1][0] = fmaf(x1, w0.x, acc[1][0]); acc[1][1] = fmaf(x1, w0.y, acc[1][1]);
            acc[1][2] = fmaf(x1, w0.z, acc[1][2]); acc[1][3] = fmaf(x1, w0.w, acc[1][3]);
            acc[1][4] = fmaf(x1, w1.x, acc[1][4]); acc[1][5] = fmaf(x1, w1.y, acc[1][5]);
            acc[1][6] = fmaf(x1, w1.z, acc[1][6]); acc[1][7] = fmaf(x1, w1.w, acc[1][7]);
            acc[2][0] = fmaf(x2, w0.x, acc[2][0]); acc[2][1] = fmaf(x2, w0.y, acc[2][1]);
            acc[2][2] = fmaf(x2, w0.z, acc[2][2]); acc[2][3] = fmaf(x2, w0.w, acc[2][3]);
            acc[2][4] = fmaf(x2, w1.x, acc[2][4]); acc[2][5] = fmaf(x2, w1.y, acc[2][5]);
            acc[2][6] = fmaf(x2, w1.z, acc[2][6]); acc[2][7] = fmaf(x2, w1.w, acc[2][7]);
            acc[3][0] = fmaf(x3, w0.x, acc[3][0]); acc[3][1] = fmaf(x3, w0.y, acc[3][1]);
            acc[3][2] = fmaf(x3, w0.z, acc[3][2]); acc[3][3] = fmaf(x3, w0.w, acc[3][3]);
            acc[3][4] = fmaf(x3, w1.x, acc[3][4]); acc[3][5] = fmaf(x3, w1.y, acc[3][5]);
            acc[3][6] = fmaf(x3, w1.z, acc[3][6]); acc[3][7] = fmaf(x3, w1.w, acc[3][7]);
        }
    }

#pragma unroll
    for (int j = 0; j < 4; ++j) {
        int row = row0 + 4 * rt + j;
        if (row < nrows) {
            float dv = dinv[row];
            uint4 o;
            o.x = pack2(acc[j][0] * dv, acc[j][1] * dv);
            o.y = pack2(acc[j][2] * dv, acc[j][3] * dv);
            o.z = pack2(acc[j][4] * dv, acc[j][5] * dv);
            o.w = pack2(acc[j][6] * dv, acc[j][7] * dv);
            *(uint4*)(out + (size_t)row * NFEAT + 8 * ct) = o;
        }
    }
}

// ---------------- aggregation + relu (layer 1), wave-per-node, bf16 gather ----------------
// lane half (0/1) = edge parity, c = lane&31 loads ushort4 (4 bf16) chunk. Row = 256B.
__global__ __launch_bounds__(256) void agg_relu_kernel(const ushort4* __restrict__ hp,
                                                       const int* __restrict__ row_start,
                                                       const int* __restrict__ deg,
                                                       const int* __restrict__ csr_src,
                                                       const float* __restrict__ dinv,
                                                       const float4* __restrict__ bias,
                                                       float4* __restrict__ out, int N) {
    const int wid = (blockIdx.x * 256 + threadIdx.x) >> 6;
    if (wid >= N) return;
    const int lane = threadIdx.x & 63;
    const int half = lane >> 5;
    const int c = lane & 31;
    float4 acc = make_float4(0.f, 0.f, 0.f, 0.f);
    if (!half) acc_bf4(acc, hp[(size_t)wid * 32 + c]);   // self-loop
    const int s = row_start[wid];
    const int d = deg[wid];
    int i = 0;
    for (; i + 16 <= d; i += 16) {
        int u[8];
#pragma unroll
        for (int j = 0; j < 8; ++j) u[j] = csr_src[s + i + 2 * j + half];
        ushort4 a[8];
#pragma unroll
        for (int j = 0; j < 8; ++j) a[j] = hp[(size_t)u[j] * 32 + c];
#pragma unroll
        for (int j = 0; j < 8; ++j) acc_bf4(acc, a[j]);
    }
    for (; i + 4 <= d; i += 4) {
        int u0 = csr_src[s + i + half];
        int u1 = csr_src[s + i + 2 + half];
        ushort4 a0 = hp[(size_t)u0 * 32 + c];
        ushort4 a1 = hp[(size_t)u1 * 32 + c];
        acc_bf4(acc, a0); acc_bf4(acc, a1);
    }
    for (; i + 2 <= d; i += 2) {
        int u = csr_src[s + i + half];
        acc_bf4(acc, hp[(size_t)u * 32 + c]);
    }
    if (i + half < d) {
        int u = csr_src[s + i + half];
        acc_bf4(acc, hp[(size_t)u * 32 + c]);
    }
    acc.x += __shfl_xor(acc.x, 32);
    acc.y += __shfl_xor(acc.y, 32);
    acc.z += __shfl_xor(acc.z, 32);
    acc.w += __shfl_xor(acc.w, 32);
    const float dv = dinv[wid];
    const float4 bb = bias[c];
    float4 val;
    val.x = fmaxf(fmaf(acc.x, dv, bb.x), 0.f);
    val.y = fmaxf(fmaf(acc.y, dv, bb.y), 0.f);
    val.z = fmaxf(fmaf(acc.z, dv, bb.z), 0.f);
    val.w = fmaxf(fmaf(acc.w, dv, bb.w), 0.f);
    if (!half) out[(size_t)wid * 32 + c] = val;
}

// ---------------- aggregation + relu + dot(lin_W) + pool-sum (layer 2 fused), bf16 gather ----------------
__global__ __launch_bounds__(256) void agg_pool_kernel(const ushort4* __restrict__ hp,
                                                       const int* __restrict__ row_start,
                                                       const int* __restrict__ deg,
                                                       const int* __restrict__ csr_src,
                                                       const float* __restrict__ dinv,
                                                       const float4* __restrict__ bias,
                                                       const float4* __restrict__ linW,
                                                       const int* __restrict__ batch,
                                                       float* __restrict__ gsum, int N) {
    const int wid = (blockIdx.x * 256 + threadIdx.x) >> 6;
    if (wid >= N) return;
    const int lane = threadIdx.x & 63;
    const int half = lane >> 5;
    const int c = lane & 31;
    float4 acc = make_float4(0.f, 0.f, 0.f, 0.f);
    if (!half) acc_bf4(acc, hp[(size_t)wid * 32 + c]);
    const int s = row_start[wid];
    const int d = deg[wid];
    int i = 0;
    for (; i + 16 <= d; i += 16) {
        int u[8];
#pragma unroll
        for (int j = 0; j < 8; ++j) u[j] = csr_src[s + i + 2 * j + half];
        ushort4 a[8];
#pragma unroll
        for (int j = 0; j < 8; ++j) a[j] = hp[(size_t)u[j] * 32 + c];
#pragma unroll
        for (int j = 0; j < 8; ++j) acc_bf4(acc, a[j]);
    }
    for (; i + 4 <= d; i += 4) {
        int u0 = csr_src[s + i + half];
        int u1 = csr_src[s + i + 2 + half];
        ushort4 a0 = hp[(size_t)u0 * 32 + c];
        ushort4 a1 = hp[(size_t)u1 * 32 + c];
        acc_bf4(acc, a0); acc_bf4(acc, a1);
    }
    for (; i + 2 <= d; i += 2) {
        int u = csr_src[s + i + half];
        acc_bf4(acc, hp[(size_t)u * 32 + c]);
    }
    if (i + half < d) {
        int u = csr_src[s + i + half];
        acc_bf4(acc, hp[(size_t)u * 32 + c]);
    }
    acc.x += __shfl_xor(acc.x, 32);
    acc.y += __shfl_xor(acc.y, 32);
    acc.z += __shfl_xor(acc.z, 32);
    acc.w += __shfl_xor(acc.w, 32);
    const float dv = dinv[wid];
    const float4 bb = bias[c];
    const float4 lw = linW[c];
    float sc = fmaxf(fmaf(acc.x, dv, bb.x), 0.f) * lw.x
             + fmaxf(fmaf(acc.y, dv, bb.y), 0.f) * lw.y
             + fmaxf(fmaf(acc.z, dv, bb.z), 0.f) * lw.z
             + fmaxf(fmaf(acc.w, dv, bb.w), 0.f) * lw.w;
#pragma unroll
    for (int off = 16; off; off >>= 1) sc += __shfl_xor(sc, off);
    if (lane == 0) atomicAdd(&gsum[batch[wid]], sc);
}

// ---------------- finalize ----------------
__global__ void finalize_kernel(const float* __restrict__ gsum, const float* __restrict__ gcnt,
                                const float* __restrict__ linb, float* __restrict__ out, int G) {
    int g = blockIdx.x * blockDim.x + threadIdx.x;
    if (g < G) out[g] = gsum[g] / fmaxf(gcnt[g], 1.0f) + linb[0];
}

extern "C" void kernel_launch(void* const* d_in, const int* in_sizes, int n_in,
                              void* d_out, int out_size, void* d_ws, size_t ws_size,
                              hipStream_t stream) {
    const float* x    = (const float*)d_in[0];
    const int*   eidx = (const int*)d_in[1];
    const int*   batch= (const int*)d_in[2];
    const float* W1   = (const float*)d_in[3];
    const float* b1   = (const float*)d_in[4];
    const float* W2   = (const float*)d_in[5];
    const float* b2   = (const float*)d_in[6];
    const float* linW = (const float*)d_in[7];
    const float* linb = (const float*)d_in[8];
    float* out = (float*)d_out;

    const int N = in_sizes[0] / NFEAT;   // 50000
    const int E = in_sizes[1] / 2;       // 800000
    const int G = out_size;              // 256
    const int* src = eidx;
    const int* dst = eidx + E;
    const int NB = (N + 1023) / 1024;

    // workspace layout
    char* p = (char*)d_ws;
    unsigned short* hpBf = (unsigned short*)p; p += (size_t)N * NFEAT * sizeof(unsigned short); // 12.8MB
    float* hpB      = (float*)p; p += (size_t)N * NFEAT * sizeof(float);                        // 25.6MB
    int*   csr_src  = (int*)p;   p += (size_t)E * sizeof(int);
    int*   row_start= (int*)p;   p += (size_t)(N + 4) * sizeof(int);
    int*   cursor   = (int*)p;   p += (size_t)N * sizeof(int);
    float* dinv     = (float*)p; p += (size_t)N * sizeof(float);
    int*   deg      = (int*)p;   p += (size_t)N * sizeof(int);
    float* gsum     = (float*)p; p += (size_t)G * sizeof(float);
    float* gcnt     = (float*)p; p += (size_t)G * sizeof(float);
    int*   bsum     = (int*)p;   p += 64 * sizeof(int);
    int*   boff     = (int*)p;   p += 64 * sizeof(int);
    (void)ws_size; (void)n_in;

    hipMemsetAsync(deg, 0, (size_t)(N + 2 * G) * sizeof(float), stream);

    count_deg_kernel<<<(E + 255) / 256, 256, 0, stream>>>(dst, deg, E);
    node_init_kernel<<<(N + 255) / 256, 256, 0, stream>>>(deg, batch, dinv, gcnt, N);
    scan_partial_kernel<<<NB, 256, 0, stream>>>(deg, bsum, N);
    scan_offsets_kernel<<<1, 64, 0, stream>>>(bsum, boff, NB);
    scan_final_kernel<<<NB, 256, 0, stream>>>(deg, boff, row_start, cursor, N);
    csr_fill_kernel<<<(E + 255) / 256, 256, 0, stream>>>(src, dst, cursor, csr_src, E);

    // layer 1: hpBf = bf16((x@W1)*dinv); hpB = relu(agg) in f32
    gemm_scale_kernel<<<(N + 63) / 64, 256, 0, stream>>>(x, W1, dinv, hpBf, N);
    agg_relu_kernel<<<(N * 64 + 255) / 256, 256, 0, stream>>>((const ushort4*)hpBf, row_start, deg,
                                                              csr_src, dinv, (const float4*)b1,
                                                              (float4*)hpB, N);
    // layer 2: hpBf = bf16((hpB@W2)*dinv); fused agg+pool
    gemm_scale_kernel<<<(N + 63) / 64, 256, 0, stream>>>(hpB, W2, dinv, hpBf, N);
    agg_pool_kernel<<<(N * 64 + 255) / 256, 256, 0, stream>>>((const ushort4*)hpBf, row_start, deg,
                                                              csr_src, dinv, (const float4*)b2,
                                                              (const float4*)linW, batch, gsum, N);
    finalize_kernel<<<(G + 63) / 64, 64, 0, stream>>>(gsum, gcnt, linb, out, G);
}

// Round 4
// 332.331 us; speedup vs baseline: 1.2859x; 1.0123x over previous
//
#include <hip/hip_runtime.h>

#define NFEAT 128

typedef unsigned int uint;

__device__ inline float bf2f(unsigned short u) {
    return __uint_as_float(((uint)u) << 16);
}
__device__ inline unsigned short f2bf(float f) {   // round-nearest-even
    uint u = __float_as_uint(f);
    return (unsigned short)((u + 0x7fffu + ((u >> 16) & 1u)) >> 16);
}
__device__ inline uint pack2(float lo, float hi) {
    return (uint)f2bf(lo) | ((uint)f2bf(hi) << 16);
}
__device__ inline void acc_bf4(float4& acc, ushort4 a) {
    acc.x += bf2f(a.x); acc.y += bf2f(a.y); acc.z += bf2f(a.z); acc.w += bf2f(a.w);
}

// ---------------- degree count ----------------
__global__ void count_deg_kernel(const int* __restrict__ dst, int* __restrict__ deg, int E) {
    int e = blockIdx.x * blockDim.x + threadIdx.x;
    if (e < E) atomicAdd(&deg[dst[e]], 1);
}

// ---------------- dinv + per-graph node counts ----------------
__global__ void node_init_kernel(const int* __restrict__ deg, const int* __restrict__ batch,
                                 float* __restrict__ dinv, float* __restrict__ gcnt, int N) {
    int v = blockIdx.x * blockDim.x + threadIdx.x;
    if (v < N) {
        dinv[v] = rsqrtf((float)(deg[v] + 1));   // +1 self-loop
        atomicAdd(&gcnt[batch[v]], 1.0f);
    }
}

// ---------------- multi-block scan, stage 1 ----------------
__global__ __launch_bounds__(256) void scan_partial_kernel(const int* __restrict__ deg,
                                                           int* __restrict__ bsum, int n) {
    __shared__ int sm[4];
    const int tid = threadIdx.x;
    const int base = blockIdx.x * 1024 + tid * 4;
    int s = 0;
#pragma unroll
    for (int j = 0; j < 4; ++j) s += (base + j < n) ? deg[base + j] : 0;
#pragma unroll
    for (int off = 32; off; off >>= 1) s += __shfl_down(s, off);
    if ((tid & 63) == 0) sm[tid >> 6] = s;
    __syncthreads();
    if (tid == 0) bsum[blockIdx.x] = sm[0] + sm[1] + sm[2] + sm[3];
}

// ---------------- stage 2: exclusive scan of block sums ----------------
__global__ __launch_bounds__(64) void scan_offsets_kernel(const int* __restrict__ bsum,
                                                          int* __restrict__ boff, int nb) {
    const int l = threadIdx.x;
    int orig = (l < nb) ? bsum[l] : 0;
    int v = orig;
#pragma unroll
    for (int off = 1; off < 64; off <<= 1) {
        int t = __shfl_up(v, off);
        if (l >= off) v += t;
    }
    if (l < nb) boff[l] = v - orig;
}

// ---------------- stage 3: final scan ----------------
__global__ __launch_bounds__(256) void scan_final_kernel(const int* __restrict__ deg,
                                                         const int* __restrict__ boff,
                                                         int* __restrict__ row_start,
                                                         int* __restrict__ cursor, int n) {
    __shared__ int wsum[4];
    const int tid = threadIdx.x;
    const int lane = tid & 63;
    const int w = tid >> 6;
    const int base = blockIdx.x * 1024 + tid * 4;
    int v[4];
    int s = 0;
#pragma unroll
    for (int j = 0; j < 4; ++j) {
        v[j] = (base + j < n) ? deg[base + j] : 0;
        s += v[j];
    }
    int incl = s;
#pragma unroll
    for (int off = 1; off < 64; off <<= 1) {
        int t = __shfl_up(incl, off);
        if (lane >= off) incl += t;
    }
    if (lane == 63) wsum[w] = incl;
    __syncthreads();
    int woff = 0;
    for (int i = 0; i < w; ++i) woff += wsum[i];
    int run = boff[blockIdx.x] + woff + (incl - s);
#pragma unroll
    for (int j = 0; j < 4; ++j) {
        if (base + j < n) { row_start[base + j] = run; cursor[base + j] = run; }
        run += v[j];
    }
}

// ---------------- CSR fill ----------------
__global__ void csr_fill_kernel(const int* __restrict__ src, const int* __restrict__ dst,
                                int* __restrict__ cursor, int* __restrict__ csr_src, int E) {
    int e = blockIdx.x * blockDim.x + threadIdx.x;
    if (e < E) {
        int pos = atomicAdd(&cursor[dst[e]], 1);
        csr_src[pos] = src[e];
    }
}

// ---------------- GEMM: out_bf16[r][c] = (sum_k X[r][k]*W[k][c]) * dinv[r] ----------------
__global__ __launch_bounds__(256) void gemm_scale_kernel(const float* __restrict__ X,
                                                         const float* __restrict__ W,
                                                         const float* __restrict__ dinv,
                                                         unsigned short* __restrict__ out,
                                                         int nrows) {
    __shared__ float xs[64][132];
    __shared__ float ws[64][128];
    const int tid = threadIdx.x;
    const int row0 = blockIdx.x * 64;
    const int rt = tid >> 4;
    const int ct = tid & 15;

    for (int idx = tid; idx < 64 * 32; idx += 256) {
        int r = idx >> 5, q = idx & 31;
        float4 val = make_float4(0.f, 0.f, 0.f, 0.f);
        if (row0 + r < nrows) val = ((const float4*)(X + (size_t)(row0 + r) * NFEAT))[q];
        *(float4*)&xs[r][q * 4] = val;
    }

    float acc[4][8];
#pragma unroll
    for (int j = 0; j < 4; ++j)
#pragma unroll
        for (int i = 0; i < 8; ++i) acc[j][i] = 0.f;

    for (int p = 0; p < 2; ++p) {
        __syncthreads();
        for (int idx = tid; idx < 64 * 32; idx += 256) {
            int kk = idx >> 5, q = idx & 31;
            *(float4*)&ws[kk][q * 4] = ((const float4*)(W + (size_t)(p * 64 + kk) * NFEAT))[q];
        }
        __syncthreads();
#pragma unroll 4
        for (int k = 0; k < 64; ++k) {
            const int ka = p * 64 + k;
            float x0 = xs[4 * rt + 0][ka];
            float x1 = xs[4 * rt + 1][ka];
            float x2 = xs[4 * rt + 2][ka];
            float x3 = xs[4 * rt + 3][ka];
            float4 w0 = *(const float4*)&ws[k][8 * ct];
            float4 w1 = *(const float4*)&ws[k][8 * ct + 4];
            acc[0][0] = fmaf(x0, w0.x, acc[0][0]); acc[0][1] = fmaf(x0, w0.y, acc[0][1]);
            acc[0][2] = fmaf(x0, w0.z, acc[0][2]); acc[0][3] = fmaf(x0, w0.w, acc[0][3]);
            acc[0][4] = fmaf(x0, w1.x, acc[0][4]); acc[0][5] = fmaf(x0, w1.y, acc[0][5]);
            acc[0][6] = fmaf(x0, w1.z, acc[0][6]); acc[0][7] = fmaf(x0, w1.w, acc[0][7]);
            acc[1][0] = fmaf(x1, w0.x, acc[1][0]); acc[1][1] = fmaf(x1, w0.y, acc[1][1]);
            acc[1][2] = fmaf(x1, w0.z, acc[1][2]); acc[1][3] = fmaf(x1, w0.w, acc[1][3]);
            acc[1][4] = fmaf(x1, w1.x, acc[1][4]); acc[1][5] = fmaf(x1, w1.y, acc[1][5]);
            acc[1][6] = fmaf(x1, w1.z, acc[1][6]); acc[1][7] = fmaf(x1, w1.w, acc[1][7]);
            acc[2][0] = fmaf(x2, w0.x, acc[2][0]); acc[2][1] = fmaf(x2, w0.y, acc[2][1]);
            acc[2][2] = fmaf(x2, w0.z, acc[2][2]); acc[2][3] = fmaf(x2, w0.w, acc[2][3]);
            acc[2][4] = fmaf(x2, w1.x, acc[2][4]); acc[2][5] = fmaf(x2, w1.y, acc[2][5]);
            acc[2][6] = fmaf(x2, w1.z, acc[2][6]); acc[2][7] = fmaf(x2, w1.w, acc[2][7]);
            acc[3][0] = fmaf(x3, w0.x, acc[3][0]); acc[3][1] = fmaf(x3, w0.y, acc[3][1]);
            acc[3][2] = fmaf(x3, w0.z, acc[3][2]); acc[3][3] = fmaf(x3, w0.w, acc[3][3]);
            acc[3][4] = fmaf(x3, w1.x, acc[3][4]); acc[3][5] = fmaf(x3, w1.y, acc[3][5]);
            acc[3][6] = fmaf(x3, w1.z, acc[3][6]); acc[3][7] = fmaf(x3, w1.w, acc[3][7]);
        }
    }

#pragma unroll
    for (int j = 0; j < 4; ++j) {
        int row = row0 + 4 * rt + j;
        if (row < nrows) {
            float dv = dinv[row];
            uint4 o;
            o.x = pack2(acc[j][0] * dv, acc[j][1] * dv);
            o.y = pack2(acc[j][2] * dv, acc[j][3] * dv);
            o.z = pack2(acc[j][4] * dv, acc[j][5] * dv);
            o.w = pack2(acc[j][6] * dv, acc[j][7] * dv);
            *(uint4*)(out + (size_t)row * NFEAT + 8 * ct) = o;
        }
    }
}

// ---------------- shared aggregation body: all gathers issued in independent flights ----------------
// Wave per node. half = edge parity, c = lane&31 loads ushort4 chunk (row = 256B bf16).
// Main loop: 16 edges per flight (8 independent gather instrs). Tail: ONE predicated
// 16-edge flight (clamped idx, masked accumulate) -> no chained dependent tail.
__device__ inline float4 agg_gather(const ushort4* __restrict__ hp,
                                    const int* __restrict__ csr_src,
                                    int s, int d, int half, int c, int wid) {
    float4 acc = make_float4(0.f, 0.f, 0.f, 0.f);
    if (!half) acc_bf4(acc, hp[(size_t)wid * 32 + c]);   // self-loop
    int i = 0;
    for (; i + 16 <= d; i += 16) {
        int u[8];
#pragma unroll
        for (int j = 0; j < 8; ++j) u[j] = csr_src[s + i + 2 * j + half];
        ushort4 a[8];
#pragma unroll
        for (int j = 0; j < 8; ++j) a[j] = hp[(size_t)u[j] * 32 + c];
#pragma unroll
        for (int j = 0; j < 8; ++j) acc_bf4(acc, a[j]);
    }
    if (i < d) {
        int u[8];
#pragma unroll
        for (int j = 0; j < 8; ++j) {
            int e = i + 2 * j + half;
            u[j] = csr_src[s + (e < d ? e : d - 1)];   // clamped: stays a valid row
        }
        ushort4 a[8];
#pragma unroll
        for (int j = 0; j < 8; ++j) a[j] = hp[(size_t)u[j] * 32 + c];
#pragma unroll
        for (int j = 0; j < 8; ++j) {
            if (i + 2 * j + half < d) acc_bf4(acc, a[j]);   // masked accumulate
        }
    }
    // merge halves
    acc.x += __shfl_xor(acc.x, 32);
    acc.y += __shfl_xor(acc.y, 32);
    acc.z += __shfl_xor(acc.z, 32);
    acc.w += __shfl_xor(acc.w, 32);
    return acc;
}

// ---------------- aggregation + relu (layer 1) ----------------
__global__ __launch_bounds__(256) void agg_relu_kernel(const ushort4* __restrict__ hp,
                                                       const int* __restrict__ row_start,
                                                       const int* __restrict__ deg,
                                                       const int* __restrict__ csr_src,
                                                       const float* __restrict__ dinv,
                                                       const float4* __restrict__ bias,
                                                       float4* __restrict__ out, int N) {
    const int wid = (blockIdx.x * 256 + threadIdx.x) >> 6;
    if (wid >= N) return;
    const int lane = threadIdx.x & 63;
    const int half = lane >> 5;
    const int c = lane & 31;
    float4 acc = agg_gather(hp, csr_src, row_start[wid], deg[wid], half, c, wid);
    const float dv = dinv[wid];
    const float4 bb = bias[c];
    float4 val;
    val.x = fmaxf(fmaf(acc.x, dv, bb.x), 0.f);
    val.y = fmaxf(fmaf(acc.y, dv, bb.y), 0.f);
    val.z = fmaxf(fmaf(acc.z, dv, bb.z), 0.f);
    val.w = fmaxf(fmaf(acc.w, dv, bb.w), 0.f);
    if (!half) out[(size_t)wid * 32 + c] = val;
}

// ---------------- aggregation + relu + dot(lin_W) + pool-sum (layer 2 fused) ----------------
__global__ __launch_bounds__(256) void agg_pool_kernel(const ushort4* __restrict__ hp,
                                                       const int* __restrict__ row_start,
                                                       const int* __restrict__ deg,
                                                       const int* __restrict__ csr_src,
                                                       const float* __restrict__ dinv,
                                                       const float4* __restrict__ bias,
                                                       const float4* __restrict__ linW,
                                                       const int* __restrict__ batch,
                                                       float* __restrict__ gsum, int N) {
    const int wid = (blockIdx.x * 256 + threadIdx.x) >> 6;
    if (wid >= N) return;
    const int lane = threadIdx.x & 63;
    const int half = lane >> 5;
    const int c = lane & 31;
    float4 acc = agg_gather(hp, csr_src, row_start[wid], deg[wid], half, c, wid);
    const float dv = dinv[wid];
    const float4 bb = bias[c];
    const float4 lw = linW[c];
    float sc = fmaxf(fmaf(acc.x, dv, bb.x), 0.f) * lw.x
             + fmaxf(fmaf(acc.y, dv, bb.y), 0.f) * lw.y
             + fmaxf(fmaf(acc.z, dv, bb.z), 0.f) * lw.z
             + fmaxf(fmaf(acc.w, dv, bb.w), 0.f) * lw.w;
#pragma unroll
    for (int off = 16; off; off >>= 1) sc += __shfl_xor(sc, off);
    if (lane == 0) atomicAdd(&gsum[batch[wid]], sc);
}

// ---------------- finalize ----------------
__global__ void finalize_kernel(const float* __restrict__ gsum, const float* __restrict__ gcnt,
                                const float* __restrict__ linb, float* __restrict__ out, int G) {
    int g = blockIdx.x * blockDim.x + threadIdx.x;
    if (g < G) out[g] = gsum[g] / fmaxf(gcnt[g], 1.0f) + linb[0];
}

extern "C" void kernel_launch(void* const* d_in, const int* in_sizes, int n_in,
                              void* d_out, int out_size, void* d_ws, size_t ws_size,
                              hipStream_t stream) {
    const float* x    = (const float*)d_in[0];
    const int*   eidx = (const int*)d_in[1];
    const int*   batch= (const int*)d_in[2];
    const float* W1   = (const float*)d_in[3];
    const float* b1   = (const float*)d_in[4];
    const float* W2   = (const float*)d_in[5];
    const float* b2   = (const float*)d_in[6];
    const float* linW = (const float*)d_in[7];
    const float* linb = (const float*)d_in[8];
    float* out = (float*)d_out;

    const int N = in_sizes[0] / NFEAT;   // 50000
    const int E = in_sizes[1] / 2;       // 800000
    const int G = out_size;              // 256
    const int* src = eidx;
    const int* dst = eidx + E;
    const int NB = (N + 1023) / 1024;

    // workspace layout
    char* p = (char*)d_ws;
    unsigned short* hpBf = (unsigned short*)p; p += (size_t)N * NFEAT * sizeof(unsigned short);
    float* hpB      = (float*)p; p += (size_t)N * NFEAT * sizeof(float);
    int*   csr_src  = (int*)p;   p += (size_t)E * sizeof(int);
    int*   row_start= (int*)p;   p += (size_t)(N + 4) * sizeof(int);
    int*   cursor   = (int*)p;   p += (size_t)N * sizeof(int);
    float* dinv     = (float*)p; p += (size_t)N * sizeof(float);
    int*   deg      = (int*)p;   p += (size_t)N * sizeof(int);
    float* gsum     = (float*)p; p += (size_t)G * sizeof(float);
    float* gcnt     = (float*)p; p += (size_t)G * sizeof(float);
    int*   bsum     = (int*)p;   p += 64 * sizeof(int);
    int*   boff     = (int*)p;   p += 64 * sizeof(int);
    (void)ws_size; (void)n_in;

    hipMemsetAsync(deg, 0, (size_t)(N + 2 * G) * sizeof(float), stream);

    count_deg_kernel<<<(E + 255) / 256, 256, 0, stream>>>(dst, deg, E);
    node_init_kernel<<<(N + 255) / 256, 256, 0, stream>>>(deg, batch, dinv, gcnt, N);
    scan_partial_kernel<<<NB, 256, 0, stream>>>(deg, bsum, N);
    scan_offsets_kernel<<<1, 64, 0, stream>>>(bsum, boff, NB);
    scan_final_kernel<<<NB, 256, 0, stream>>>(deg, boff, row_start, cursor, N);
    csr_fill_kernel<<<(E + 255) / 256, 256, 0, stream>>>(src, dst, cursor, csr_src, E);

    // layer 1
    gemm_scale_kernel<<<(N + 63) / 64, 256, 0, stream>>>(x, W1, dinv, hpBf, N);
    agg_relu_kernel<<<(N * 64 + 255) / 256, 256, 0, stream>>>((const ushort4*)hpBf, row_start, deg,
                                                              csr_src, dinv, (const float4*)b1,
                                                              (float4*)hpB, N);
    // layer 2
    gemm_scale_kernel<<<(N + 63) / 64, 256, 0, stream>>>(hpB, W2, dinv, hpBf, N);
    agg_pool_kernel<<<(N * 64 + 255) / 256, 256, 0, stream>>>((const ushort4*)hpBf, row_start, deg,
                                                              csr_src, dinv, (const float4*)b2,
                                                              (const float4*)linW, batch, gsum, N);
    finalize_kernel<<<(G + 63) / 64, 64, 0, stream>>>(gsum, gcnt, linb, out, G);
}

// Round 5
// 326.607 us; speedup vs baseline: 1.3085x; 1.0175x over previous
//
#include <hip/hip_runtime.h>

#define NFEAT 128

typedef unsigned int uint;
typedef __attribute__((ext_vector_type(8))) short short8v;
typedef __attribute__((ext_vector_type(4))) float floatx4;

__device__ inline float bf2f(unsigned short u) {
    return __uint_as_float(((uint)u) << 16);
}
__device__ inline unsigned short f2bf(float f) {   // round-nearest-even
    uint u = __float_as_uint(f);
    return (unsigned short)((u + 0x7fffu + ((u >> 16) & 1u)) >> 16);
}
__device__ inline void acc_bf4(float4& acc, ushort4 a) {
    acc.x += bf2f(a.x); acc.y += bf2f(a.y); acc.z += bf2f(a.z); acc.w += bf2f(a.w);
}

// ---------------- degree count ----------------
__global__ void count_deg_kernel(const int* __restrict__ dst, int* __restrict__ deg, int E) {
    int e = blockIdx.x * blockDim.x + threadIdx.x;
    if (e < E) atomicAdd(&deg[dst[e]], 1);
}

// ---------------- dinv + per-graph node counts ----------------
__global__ void node_init_kernel(const int* __restrict__ deg, const int* __restrict__ batch,
                                 float* __restrict__ dinv, float* __restrict__ gcnt, int N) {
    int v = blockIdx.x * blockDim.x + threadIdx.x;
    if (v < N) {
        dinv[v] = rsqrtf((float)(deg[v] + 1));   // +1 self-loop
        atomicAdd(&gcnt[batch[v]], 1.0f);
    }
}

// ---------------- multi-block scan, stage 1 ----------------
__global__ __launch_bounds__(256) void scan_partial_kernel(const int* __restrict__ deg,
                                                           int* __restrict__ bsum, int n) {
    __shared__ int sm[4];
    const int tid = threadIdx.x;
    const int base = blockIdx.x * 1024 + tid * 4;
    int s = 0;
#pragma unroll
    for (int j = 0; j < 4; ++j) s += (base + j < n) ? deg[base + j] : 0;
#pragma unroll
    for (int off = 32; off; off >>= 1) s += __shfl_down(s, off);
    if ((tid & 63) == 0) sm[tid >> 6] = s;
    __syncthreads();
    if (tid == 0) bsum[blockIdx.x] = sm[0] + sm[1] + sm[2] + sm[3];
}

// ---------------- stage 2: exclusive scan of block sums ----------------
__global__ __launch_bounds__(64) void scan_offsets_kernel(const int* __restrict__ bsum,
                                                          int* __restrict__ boff, int nb) {
    const int l = threadIdx.x;
    int orig = (l < nb) ? bsum[l] : 0;
    int v = orig;
#pragma unroll
    for (int off = 1; off < 64; off <<= 1) {
        int t = __shfl_up(v, off);
        if (l >= off) v += t;
    }
    if (l < nb) boff[l] = v - orig;
}

// ---------------- stage 3: final scan ----------------
__global__ __launch_bounds__(256) void scan_final_kernel(const int* __restrict__ deg,
                                                         const int* __restrict__ boff,
                                                         int* __restrict__ row_start,
                                                         int* __restrict__ cursor, int n) {
    __shared__ int wsum[4];
    const int tid = threadIdx.x;
    const int lane = tid & 63;
    const int w = tid >> 6;
    const int base = blockIdx.x * 1024 + tid * 4;
    int v[4];
    int s = 0;
#pragma unroll
    for (int j = 0; j < 4; ++j) {
        v[j] = (base + j < n) ? deg[base + j] : 0;
        s += v[j];
    }
    int incl = s;
#pragma unroll
    for (int off = 1; off < 64; off <<= 1) {
        int t = __shfl_up(incl, off);
        if (lane >= off) incl += t;
    }
    if (lane == 63) wsum[w] = incl;
    __syncthreads();
    int woff = 0;
    for (int i = 0; i < w; ++i) woff += wsum[i];
    int run = boff[blockIdx.x] + woff + (incl - s);
#pragma unroll
    for (int j = 0; j < 4; ++j) {
        if (base + j < n) { row_start[base + j] = run; cursor[base + j] = run; }
        run += v[j];
    }
}

// ---------------- CSR fill ----------------
__global__ void csr_fill_kernel(const int* __restrict__ src, const int* __restrict__ dst,
                                int* __restrict__ cursor, int* __restrict__ csr_src, int E) {
    int e = blockIdx.x * blockDim.x + threadIdx.x;
    if (e < E) {
        int pos = atomicAdd(&cursor[dst[e]], 1);
        csr_src[pos] = src[e];
    }
}

// ================= MFMA GEMM (layer 1): X f32 -> split bf16 hi/lo, W f32 -> hi/lo =================
// out_bf16[r][c] = bf16( (sum_k X[r][k] W[k][c]) * dinv[r] )
// block 256 (4 waves), M-tile 64 (wave w: rows 16w..16w+15), N = 128 (8 n-tiles of 16).
// mfma_f32_16x16x32_bf16; A row = lane&15, k-group = lane>>4 (k-map shared by A and B ->
// result invariant to the true k permutation). C/D: col = lane&15, row = (lane>>4)*4+reg (m89).
__global__ __launch_bounds__(256) void gemm1_mfma_kernel(const float* __restrict__ X,
                                                         const float* __restrict__ W,
                                                         const float* __restrict__ dinv,
                                                         unsigned short* __restrict__ out,
                                                         int nrows) {
    __shared__ unsigned short xs_hi[64][72], xs_lo[64][72];    // X k-chunk, pitch 72 (16B-aligned)
    __shared__ unsigned short wt_hi[128][72], wt_lo[128][72];  // W^T k-chunk
    const int tid = threadIdx.x;
    const int w = tid >> 6, lane = tid & 63;
    const int nl = lane & 15, kg = lane >> 4;
    const int row0 = blockIdx.x * 64;

    floatx4 acc[8];
#pragma unroll
    for (int nt = 0; nt < 8; ++nt) acc[nt] = (floatx4){0.f, 0.f, 0.f, 0.f};

    for (int p = 0; p < 2; ++p) {
        __syncthreads();
        // stage X chunk [64 rows][k=64] -> hi/lo bf16
        for (int idx = tid; idx < 64 * 16; idx += 256) {
            int r = idx >> 4, q = idx & 15;
            float4 v = make_float4(0.f, 0.f, 0.f, 0.f);
            if (row0 + r < nrows)
                v = ((const float4*)(X + (size_t)(row0 + r) * NFEAT + p * 64))[q];
            ushort4 h, l;
            h.x = f2bf(v.x); l.x = f2bf(v.x - bf2f(h.x));
            h.y = f2bf(v.y); l.y = f2bf(v.y - bf2f(h.y));
            h.z = f2bf(v.z); l.z = f2bf(v.z - bf2f(h.z));
            h.w = f2bf(v.w); l.w = f2bf(v.w - bf2f(h.w));
            *(ushort4*)&xs_hi[r][q * 4] = h;
            *(ushort4*)&xs_lo[r][q * 4] = l;
        }
        // stage W chunk transposed [n=128][k=64] -> hi/lo bf16
        for (int idx = tid; idx < 64 * 32; idx += 256) {
            int kk = idx >> 5, q = idx & 31;
            float4 v = ((const float4*)(W + (size_t)(p * 64 + kk) * NFEAT))[q];
            int n = q * 4;
            unsigned short h;
            h = f2bf(v.x); wt_hi[n + 0][kk] = h; wt_lo[n + 0][kk] = f2bf(v.x - bf2f(h));
            h = f2bf(v.y); wt_hi[n + 1][kk] = h; wt_lo[n + 1][kk] = f2bf(v.y - bf2f(h));
            h = f2bf(v.z); wt_hi[n + 2][kk] = h; wt_lo[n + 2][kk] = f2bf(v.z - bf2f(h));
            h = f2bf(v.w); wt_hi[n + 3][kk] = h; wt_lo[n + 3][kk] = f2bf(v.w - bf2f(h));
        }
        __syncthreads();
#pragma unroll
        for (int kc = 0; kc < 2; ++kc) {
            const int k8 = kc * 32 + kg * 8;
            short8v ah = *(const short8v*)&xs_hi[w * 16 + nl][k8];
            short8v al = *(const short8v*)&xs_lo[w * 16 + nl][k8];
#pragma unroll
            for (int nt = 0; nt < 8; ++nt) {
                short8v bh = *(const short8v*)&wt_hi[nt * 16 + nl][k8];
                short8v bl = *(const short8v*)&wt_lo[nt * 16 + nl][k8];
                acc[nt] = __builtin_amdgcn_mfma_f32_16x16x32_bf16(ah, bh, acc[nt], 0, 0, 0);
                acc[nt] = __builtin_amdgcn_mfma_f32_16x16x32_bf16(al, bh, acc[nt], 0, 0, 0);
                acc[nt] = __builtin_amdgcn_mfma_f32_16x16x32_bf16(ah, bl, acc[nt], 0, 0, 0);
            }
        }
    }
    const int rbase = row0 + w * 16 + kg * 4;
#pragma unroll
    for (int reg = 0; reg < 4; ++reg) {
        int grow = rbase + reg;
        if (grow < nrows) {
            float dv = dinv[grow];
#pragma unroll
            for (int nt = 0; nt < 8; ++nt)
                out[(size_t)grow * NFEAT + nt * 16 + nl] = f2bf(acc[nt][reg] * dv);
        }
    }
}

// ================= MFMA GEMM (layer 2): X already bf16, W f32 -> hi/lo (2 terms) =================
__global__ __launch_bounds__(256) void gemm2_mfma_kernel(const unsigned short* __restrict__ X,
                                                         const float* __restrict__ W,
                                                         const float* __restrict__ dinv,
                                                         unsigned short* __restrict__ out,
                                                         int nrows) {
    __shared__ unsigned short xs[64][72];
    __shared__ unsigned short wt_hi[128][72], wt_lo[128][72];
    const int tid = threadIdx.x;
    const int w = tid >> 6, lane = tid & 63;
    const int nl = lane & 15, kg = lane >> 4;
    const int row0 = blockIdx.x * 64;

    floatx4 acc[8];
#pragma unroll
    for (int nt = 0; nt < 8; ++nt) acc[nt] = (floatx4){0.f, 0.f, 0.f, 0.f};

    for (int p = 0; p < 2; ++p) {
        __syncthreads();
        // stage X chunk (bf16 copy)
        for (int idx = tid; idx < 64 * 8; idx += 256) {
            int r = idx >> 3, q = idx & 7;
            short8v v = {0, 0, 0, 0, 0, 0, 0, 0};
            if (row0 + r < nrows)
                v = *(const short8v*)(X + (size_t)(row0 + r) * NFEAT + p * 64 + q * 8);
            *(short8v*)&xs[r][q * 8] = v;
        }
        // stage W chunk transposed -> hi/lo
        for (int idx = tid; idx < 64 * 32; idx += 256) {
            int kk = idx >> 5, q = idx & 31;
            float4 v = ((const float4*)(W + (size_t)(p * 64 + kk) * NFEAT))[q];
            int n = q * 4;
            unsigned short h;
            h = f2bf(v.x); wt_hi[n + 0][kk] = h; wt_lo[n + 0][kk] = f2bf(v.x - bf2f(h));
            h = f2bf(v.y); wt_hi[n + 1][kk] = h; wt_lo[n + 1][kk] = f2bf(v.y - bf2f(h));
            h = f2bf(v.z); wt_hi[n + 2][kk] = h; wt_lo[n + 2][kk] = f2bf(v.z - bf2f(h));
            h = f2bf(v.w); wt_hi[n + 3][kk] = h; wt_lo[n + 3][kk] = f2bf(v.w - bf2f(h));
        }
        __syncthreads();
#pragma unroll
        for (int kc = 0; kc < 2; ++kc) {
            const int k8 = kc * 32 + kg * 8;
            short8v a = *(const short8v*)&xs[w * 16 + nl][k8];
#pragma unroll
            for (int nt = 0; nt < 8; ++nt) {
                short8v bh = *(const short8v*)&wt_hi[nt * 16 + nl][k8];
                short8v bl = *(const short8v*)&wt_lo[nt * 16 + nl][k8];
                acc[nt] = __builtin_amdgcn_mfma_f32_16x16x32_bf16(a, bh, acc[nt], 0, 0, 0);
                acc[nt] = __builtin_amdgcn_mfma_f32_16x16x32_bf16(a, bl, acc[nt], 0, 0, 0);
            }
        }
    }
    const int rbase = row0 + w * 16 + kg * 4;
#pragma unroll
    for (int reg = 0; reg < 4; ++reg) {
        int grow = rbase + reg;
        if (grow < nrows) {
            float dv = dinv[grow];
#pragma unroll
            for (int nt = 0; nt < 8; ++nt)
                out[(size_t)grow * NFEAT + nt * 16 + nl] = f2bf(acc[nt][reg] * dv);
        }
    }
}

// ---------------- shared aggregation body (unchanged from R4) ----------------
__device__ inline float4 agg_gather(const ushort4* __restrict__ hp,
                                    const int* __restrict__ csr_src,
                                    int s, int d, int half, int c, int wid) {
    float4 acc = make_float4(0.f, 0.f, 0.f, 0.f);
    if (!half) acc_bf4(acc, hp[(size_t)wid * 32 + c]);   // self-loop
    int i = 0;
    for (; i + 16 <= d; i += 16) {
        int u[8];
#pragma unroll
        for (int j = 0; j < 8; ++j) u[j] = csr_src[s + i + 2 * j + half];
        ushort4 a[8];
#pragma unroll
        for (int j = 0; j < 8; ++j) a[j] = hp[(size_t)u[j] * 32 + c];
#pragma unroll
        for (int j = 0; j < 8; ++j) acc_bf4(acc, a[j]);
    }
    if (i < d) {
        int u[8];
#pragma unroll
        for (int j = 0; j < 8; ++j) {
            int e = i + 2 * j + half;
            u[j] = csr_src[s + (e < d ? e : d - 1)];
        }
        ushort4 a[8];
#pragma unroll
        for (int j = 0; j < 8; ++j) a[j] = hp[(size_t)u[j] * 32 + c];
#pragma unroll
        for (int j = 0; j < 8; ++j) {
            if (i + 2 * j + half < d) acc_bf4(acc, a[j]);
        }
    }
    acc.x += __shfl_xor(acc.x, 32);
    acc.y += __shfl_xor(acc.y, 32);
    acc.z += __shfl_xor(acc.z, 32);
    acc.w += __shfl_xor(acc.w, 32);
    return acc;
}

// ---------------- aggregation + relu (layer 1) -> bf16 out ----------------
__global__ __launch_bounds__(256) void agg_relu_kernel(const ushort4* __restrict__ hp,
                                                       const int* __restrict__ row_start,
                                                       const int* __restrict__ deg,
                                                       const int* __restrict__ csr_src,
                                                       const float* __restrict__ dinv,
                                                       const float4* __restrict__ bias,
                                                       unsigned short* __restrict__ out, int N) {
    const int wid = (blockIdx.x * 256 + threadIdx.x) >> 6;
    if (wid >= N) return;
    const int lane = threadIdx.x & 63;
    const int half = lane >> 5;
    const int c = lane & 31;
    float4 acc = agg_gather(hp, csr_src, row_start[wid], deg[wid], half, c, wid);
    const float dv = dinv[wid];
    const float4 bb = bias[c];
    if (!half) {
        ushort4 o;
        o.x = f2bf(fmaxf(fmaf(acc.x, dv, bb.x), 0.f));
        o.y = f2bf(fmaxf(fmaf(acc.y, dv, bb.y), 0.f));
        o.z = f2bf(fmaxf(fmaf(acc.z, dv, bb.z), 0.f));
        o.w = f2bf(fmaxf(fmaf(acc.w, dv, bb.w), 0.f));
        *(ushort4*)(out + (size_t)wid * NFEAT + c * 4) = o;
    }
}

// ---------------- aggregation + relu + dot(lin_W) + pool-sum (layer 2 fused) ----------------
__global__ __launch_bounds__(256) void agg_pool_kernel(const ushort4* __restrict__ hp,
                                                       const int* __restrict__ row_start,
                                                       const int* __restrict__ deg,
                                                       const int* __restrict__ csr_src,
                                                       const float* __restrict__ dinv,
                                                       const float4* __restrict__ bias,
                                                       const float4* __restrict__ linW,
                                                       const int* __restrict__ batch,
                                                       float* __restrict__ gsum, int N) {
    const int wid = (blockIdx.x * 256 + threadIdx.x) >> 6;
    if (wid >= N) return;
    const int lane = threadIdx.x & 63;
    const int half = lane >> 5;
    const int c = lane & 31;
    float4 acc = agg_gather(hp, csr_src, row_start[wid], deg[wid], half, c, wid);
    const float dv = dinv[wid];
    const float4 bb = bias[c];
    const float4 lw = linW[c];
    float sc = fmaxf(fmaf(acc.x, dv, bb.x), 0.f) * lw.x
             + fmaxf(fmaf(acc.y, dv, bb.y), 0.f) * lw.y
             + fmaxf(fmaf(acc.z, dv, bb.z), 0.f) * lw.z
             + fmaxf(fmaf(acc.w, dv, bb.w), 0.f) * lw.w;
#pragma unroll
    for (int off = 16; off; off >>= 1) sc += __shfl_xor(sc, off);
    if (lane == 0) atomicAdd(&gsum[batch[wid]], sc);
}

// ---------------- finalize ----------------
__global__ void finalize_kernel(const float* __restrict__ gsum, const float* __restrict__ gcnt,
                                const float* __restrict__ linb, float* __restrict__ out, int G) {
    int g = blockIdx.x * blockDim.x + threadIdx.x;
    if (g < G) out[g] = gsum[g] / fmaxf(gcnt[g], 1.0f) + linb[0];
}

extern "C" void kernel_launch(void* const* d_in, const int* in_sizes, int n_in,
                              void* d_out, int out_size, void* d_ws, size_t ws_size,
                              hipStream_t stream) {
    const float* x    = (const float*)d_in[0];
    const int*   eidx = (const int*)d_in[1];
    const int*   batch= (const int*)d_in[2];
    const float* W1   = (const float*)d_in[3];
    const float* b1   = (const float*)d_in[4];
    const float* W2   = (const float*)d_in[5];
    const float* b2   = (const float*)d_in[6];
    const float* linW = (const float*)d_in[7];
    const float* linb = (const float*)d_in[8];
    float* out = (float*)d_out;

    const int N = in_sizes[0] / NFEAT;   // 50000
    const int E = in_sizes[1] / 2;       // 800000
    const int G = out_size;              // 256
    const int* src = eidx;
    const int* dst = eidx + E;
    const int NB = (N + 1023) / 1024;

    // workspace layout
    char* p = (char*)d_ws;
    unsigned short* hpBf = (unsigned short*)p; p += (size_t)N * NFEAT * sizeof(unsigned short); // gemm out (gathered)
    unsigned short* h1Bf = (unsigned short*)p; p += (size_t)N * NFEAT * sizeof(unsigned short); // layer-1 activations
    int*   csr_src  = (int*)p;   p += (size_t)E * sizeof(int);
    int*   row_start= (int*)p;   p += (size_t)(N + 4) * sizeof(int);
    int*   cursor   = (int*)p;   p += (size_t)N * sizeof(int);
    float* dinv     = (float*)p; p += (size_t)N * sizeof(float);
    int*   deg      = (int*)p;   p += (size_t)N * sizeof(int);
    float* gsum     = (float*)p; p += (size_t)G * sizeof(float);
    float* gcnt     = (float*)p; p += (size_t)G * sizeof(float);
    int*   bsum     = (int*)p;   p += 64 * sizeof(int);
    int*   boff     = (int*)p;   p += 64 * sizeof(int);
    (void)ws_size; (void)n_in;

    hipMemsetAsync(deg, 0, (size_t)(N + 2 * G) * sizeof(float), stream);

    count_deg_kernel<<<(E + 255) / 256, 256, 0, stream>>>(dst, deg, E);
    node_init_kernel<<<(N + 255) / 256, 256, 0, stream>>>(deg, batch, dinv, gcnt, N);
    scan_partial_kernel<<<NB, 256, 0, stream>>>(deg, bsum, N);
    scan_offsets_kernel<<<1, 64, 0, stream>>>(bsum, boff, NB);
    scan_final_kernel<<<NB, 256, 0, stream>>>(deg, boff, row_start, cursor, N);
    csr_fill_kernel<<<(E + 255) / 256, 256, 0, stream>>>(src, dst, cursor, csr_src, E);

    // layer 1: hpBf = bf16((x@W1)*dinv)  [split-precision MFMA]
    gemm1_mfma_kernel<<<(N + 63) / 64, 256, 0, stream>>>(x, W1, dinv, hpBf, N);
    agg_relu_kernel<<<(N * 64 + 255) / 256, 256, 0, stream>>>((const ushort4*)hpBf, row_start, deg,
                                                              csr_src, dinv, (const float4*)b1,
                                                              h1Bf, N);
    // layer 2: hpBf = bf16((h1@W2)*dinv)  [X already bf16, 2-term MFMA]
    gemm2_mfma_kernel<<<(N + 63) / 64, 256, 0, stream>>>(h1Bf, W2, dinv, hpBf, N);
    agg_pool_kernel<<<(N * 64 + 255) / 256, 256, 0, stream>>>((const ushort4*)hpBf, row_start, deg,
                                                              csr_src, dinv, (const float4*)b2,
                                                              (const float4*)linW, batch, gsum, N);
    finalize_kernel<<<(G + 63) / 64, 64, 0, stream>>>(gsum, gcnt, linb, out, G);
}